// Round 4
// baseline (66.428 us; speedup 1.0000x reference)
//
#include <hip/hip_runtime.h>
#include <hip/hip_bf16.h>

// Problem constants
#define BB     32
#define HIDD   128
#define ATT    128
#define SS     8192            // T*N positions per batch
#define CH     64              // rows per chunk
#define NCHPB  8               // chunks per block
#define BLKPB  16              // blocks per batch = SS/(CH*NCHPB)
#define PART_STRIDE 130        // [m, l, acc[128]]

typedef float f32x4 __attribute__((ext_vector_type(4)));
typedef short s16x8 __attribute__((ext_vector_type(8)));

__device__ inline unsigned short f2bf(float x) {
    unsigned u = __float_as_uint(x);
    u += 0x7FFFu + ((u >> 16) & 1u);   // RNE
    return (unsigned short)(u >> 16);
}
__device__ inline float fast_tanh(float x) {
    x = fminf(15.f, fmaxf(-15.f, x));
    float e2 = __expf(2.f * x);
    return (e2 - 1.f) * __builtin_amdgcn_rcpf(e2 + 1.f);
}
__device__ inline unsigned cvt_pk_bf16(float a, float b) {
    unsigned r;
    asm("v_cvt_pk_bf16_f32 %0, %1, %2" : "=v"(r) : "v"(a), "v"(b));
    return r;   // low16 = bf16(a), high16 = bf16(b), RNE
}

// ---- prep (merged): blocks 0..63 -> Wh_w f32->bf16; blocks 64..95 -> bias2 ----
__global__ void prep_kernel(const float* __restrict__ whw,
                            unsigned short* __restrict__ wbf,
                            const float* __restrict__ cur,
                            const float* __restrict__ wxw,
                            const float* __restrict__ wxb,
                            const float* __restrict__ whb,
                            float* __restrict__ bias2) {
    if (blockIdx.x < 64) {
        int i = blockIdx.x * 256 + threadIdx.x;   // 16384 total
        wbf[i] = f2bf(whw[i]);
    } else {
        __shared__ float sc[HIDD];
        int b = blockIdx.x - 64;
        int a = threadIdx.x;
        if (a < HIDD) sc[a] = cur[b * HIDD + a];
        __syncthreads();
        if (a < ATT) {
            float d = 0.f;
#pragma unroll 8
            for (int h = 0; h < HIDD; ++h) d += sc[h] * wxw[a * HIDD + h];
            bias2[b * ATT + a] = d + wxb[a] + whb[a];
        }
    }
}

// ---- main: per block: 8 chunks of 64 rows, double-buffered f32 LDS staged by
//      global_load_lds (pure DMA, source-swizzled), counted vmcnt pipeline,
//      swapped MFMA (D = W x H^T) + in-lane v-dot, online softmax across chunks ----
__global__ __launch_bounds__(256, 2) void attn_main_kernel(
    const float* __restrict__ hist,
    const unsigned short* __restrict__ wbf,
    const float* __restrict__ bias2,
    const float* __restrict__ vw,
    float* __restrict__ partials)
{
    __shared__ __align__(16) float sBuf[2][CH * HIDD];   // 2 x 32 KB, swizzled
    __shared__ float sScoreP[4][CH];                     // per-wave partial scores
    __shared__ float sScore[CH];
    __shared__ float sAcc[8][HIDD];                      // 4 KB

    const int tid  = threadIdx.x;
    const int bid  = blockIdx.x;
    const int b    = bid / BLKPB;
    const int blk  = bid % BLKPB;
    const int chunk0 = blk * NCHPB;
    const int lane = tid & 63;
    const int wid  = tid >> 6;
    const int l15  = lane & 15;
    const int lg   = lane >> 4;
    const int sg   = tid >> 5;      // 0..7 (s-group for accumulation)
    const int uu   = tid & 31;      // 16B-unit (4 f32) column for accumulation

    // ---- this wave's 2 a-tiles: W fragments (A operand), bias, v in registers ----
    s16x8 wfrag[2][4];
    float bia[2][4], vv[2][4];
#pragma unroll
    for (int j = 0; j < 2; ++j) {
        int arow = (wid * 2 + j) * 16 + l15;
#pragma unroll
        for (int kk = 0; kk < 4; ++kk)
            wfrag[j][kk] = *(const s16x8*)(wbf + arow * HIDD + kk * 32 + lg * 8);
#pragma unroll
        for (int r = 0; r < 4; ++r) {
            int a = (wid * 2 + j) * 16 + lg * 4 + r;
            bia[j][r] = bias2[b * ATT + a];
            vv[j][r]  = vw[a];
        }
    }

    // ---- DMA stage: chunk c -> sBuf[buf]; source pre-swizzled (dest is linear) ----
    // logical 16B unit (row,u), u in 0..31; swizzled su = u ^ ((row&7)<<2)
    auto stage = [&](int c, int buf) {
        const float* src = hist + ((size_t)b * SS + (size_t)(chunk0 + c) * CH) * HIDD;
#pragma unroll
        for (int i = 0; i < 8; ++i) {
            int d   = (i * 4 + wid) * 64 + lane;   // dest 16B-unit index 0..2047
            int row = d >> 5;
            int u   = d & 31;
            int su  = u ^ ((row & 7) << 2);
            const float* sp = src + row * HIDD + su * 4;
            float* lp = &sBuf[buf][(i * 4 + wid) * 256];   // wave-uniform base
            __builtin_amdgcn_global_load_lds(
                (const __attribute__((address_space(1))) void*)sp,
                (__attribute__((address_space(3))) void*)lp, 16, 0, 0);
        }
    };

    stage(0, 0);
    stage(1, 1);

    float m_run = -1e30f, l_run = 0.f;
    f32x4 acc4 = {0.f, 0.f, 0.f, 0.f};

#pragma unroll
    for (int c = 0; c < NCHPB; ++c) {
        const int cur = c & 1;
        // (A) own chunk-c DMA landed (counted: next chunk's 8 stay in flight)
        if (c < NCHPB - 1) asm volatile("s_waitcnt vmcnt(8)" ::: "memory");
        else               asm volatile("s_waitcnt vmcnt(0)" ::: "memory");
        __builtin_amdgcn_sched_barrier(0);
        __builtin_amdgcn_s_barrier();
        __builtin_amdgcn_sched_barrier(0);

        // ---- scores: 4 s-tiles, D[a][s] = W . H^T, v-dot in-lane ----
#pragma unroll
        for (int st = 0; st < 4; ++st) {
            int srow = st * 16 + l15;
            s16x8 hfrag[4];
#pragma unroll
            for (int kk = 0; kk < 4; ++kk) {
                int us = (kk * 8 + lg * 2) ^ ((srow & 7) << 2);
                const float* bp = &sBuf[cur][srow * HIDD + us * 4];
                f32x4 x0 = *(const f32x4*)bp;
                f32x4 x1 = *(const f32x4*)(bp + 4);
                union { s16x8 v; unsigned w[4]; } fr;
                fr.w[0] = cvt_pk_bf16(x0.x, x0.y);
                fr.w[1] = cvt_pk_bf16(x0.z, x0.w);
                fr.w[2] = cvt_pk_bf16(x1.x, x1.y);
                fr.w[3] = cvt_pk_bf16(x1.z, x1.w);
                hfrag[kk] = fr.v;
            }
            f32x4 acc0 = {0.f, 0.f, 0.f, 0.f};
            f32x4 acc1 = {0.f, 0.f, 0.f, 0.f};
#pragma unroll
            for (int kk = 0; kk < 4; ++kk) {
                acc0 = __builtin_amdgcn_mfma_f32_16x16x32_bf16(wfrag[0][kk], hfrag[kk], acc0, 0, 0, 0);
                acc1 = __builtin_amdgcn_mfma_f32_16x16x32_bf16(wfrag[1][kk], hfrag[kk], acc1, 0, 0, 0);
            }
            float p = 0.f;
#pragma unroll
            for (int r = 0; r < 4; ++r)
                p += vv[0][r] * fast_tanh(acc0[r] + bia[0][r])
                   + vv[1][r] * fast_tanh(acc1[r] + bia[1][r]);
            p += __shfl_xor(p, 16, 64);
            p += __shfl_xor(p, 32, 64);
            if (lg == 0) sScoreP[wid][st * 16 + l15] = p;
        }
        // (B) sScoreP visible to all waves
        asm volatile("s_waitcnt lgkmcnt(0)" ::: "memory");
        __builtin_amdgcn_s_barrier();

        // ---- online-softmax stats (each wave covers all 64 scores -> identical) ----
        float scv = sScoreP[0][lane] + sScoreP[1][lane] + sScoreP[2][lane] + sScoreP[3][lane];
        float mx = scv;
#pragma unroll
        for (int m = 1; m < 64; m <<= 1) mx = fmaxf(mx, __shfl_xor(mx, m, 64));
        float m_new = fmaxf(m_run, mx);
        float scale_old = __expf(m_run - m_new);
        float ev = __expf(scv - m_new);
        float es = ev;
#pragma unroll
        for (int m = 1; m < 64; m <<= 1) es += __shfl_xor(es, m, 64);
        l_run = l_run * scale_old + es;
        m_run = m_new;
        if (wid == 0) sScore[lane] = ev;
        // (C) sScore visible
        asm volatile("s_waitcnt lgkmcnt(0)" ::: "memory");
        __builtin_amdgcn_s_barrier();

        // ---- weighted accumulation (f32 history), online rescale ----
        acc4 *= scale_old;
#pragma unroll
        for (int r8 = 0; r8 < 8; ++r8) {
            int row = sg * 8 + r8;
            float w = sScore[row];
            int us = uu ^ ((row & 7) << 2);
            f32x4 h = *(const f32x4*)&sBuf[cur][row * HIDD + us * 4];
            acc4 += w * h;
        }
        // (D) all reads of sBuf[cur] retired -> safe to overwrite via DMA
        asm volatile("s_waitcnt lgkmcnt(0)" ::: "memory");
        __builtin_amdgcn_s_barrier();
        __builtin_amdgcn_sched_barrier(0);
        if (c + 2 < NCHPB) stage(c + 2, cur);
    }

    // ---- epilogue: reduce s-groups, write block partial ----
    *(f32x4*)&sAcc[sg][uu * 4] = acc4;
    asm volatile("s_waitcnt lgkmcnt(0)" ::: "memory");
    __builtin_amdgcn_s_barrier();
    float* part = partials + (size_t)(b * BLKPB + blk) * PART_STRIDE;
    if (tid == 0) { part[0] = m_run; part[1] = l_run; }
    if (tid < 128) {
        float s = 0.f;
#pragma unroll
        for (int g = 0; g < 8; ++g) s += sAcc[g][tid];
        part[2 + tid] = s;
    }
}

// ---- combine: merge block partials, add cur_h ----
__global__ void attn_combine_kernel(const float* __restrict__ cur,
                                    const float* __restrict__ partials,
                                    float* __restrict__ out)
{
    int b = blockIdx.x, h = threadIdx.x;   // 128 threads
    const float* pb = partials + (size_t)b * BLKPB * PART_STRIDE;
    float M = -INFINITY;
    for (int c = 0; c < BLKPB; ++c) M = fmaxf(M, pb[c * PART_STRIDE]);
    float num = 0.f, den = 0.f;
    for (int c = 0; c < BLKPB; ++c) {
        float scale = __expf(pb[c * PART_STRIDE] - M);
        den += pb[c * PART_STRIDE + 1] * scale;
        num += pb[c * PART_STRIDE + 2 + h] * scale;
    }
    out[b * HIDD + h] = cur[b * HIDD + h] + num / den;
}

extern "C" void kernel_launch(void* const* d_in, const int* in_sizes, int n_in,
                              void* d_out, int out_size, void* d_ws, size_t ws_size,
                              hipStream_t stream) {
    const float* cur  = (const float*)d_in[0];
    const float* hist = (const float*)d_in[1];
    const float* wxw  = (const float*)d_in[2];
    const float* wxb  = (const float*)d_in[3];
    const float* whw  = (const float*)d_in[4];
    const float* whb  = (const float*)d_in[5];
    const float* vw   = (const float*)d_in[6];
    float* out = (float*)d_out;

    // workspace: [wbf 32KB][bias2 16KB][partials 512*130 f32]
    unsigned short* wbf = (unsigned short*)d_ws;
    float* bias2    = (float*)((char*)d_ws + 32768);
    float* partials = (float*)((char*)d_ws + 32768 + 16384);

    prep_kernel<<<96, 256, 0, stream>>>(whw, wbf, cur, wxw, wxb, whb, bias2);
    attn_main_kernel<<<BB * BLKPB, 256, 0, stream>>>(hist, wbf, bias2, vw, partials);
    attn_combine_kernel<<<BB, HIDD, 0, stream>>>(cur, partials, out);
}